// Round 7
// baseline (476.049 us; speedup 1.0000x reference)
//
#include <hip/hip_runtime.h>
#include <hip/hip_bf16.h>

#define EPS_ 1e-5f

typedef __attribute__((ext_vector_type(8))) short bf16x8;
typedef __attribute__((ext_vector_type(4))) float f32x4;

static __device__ __forceinline__ float bf2f(unsigned short u) {
  return __uint_as_float(((unsigned int)u) << 16);
}
static __device__ __forceinline__ unsigned short f2bf(float f) {
  unsigned int u = __float_as_uint(f);
  u += 0x7FFFu + ((u >> 16) & 1u);   // RNE
  return (unsigned short)(u >> 16);
}

// tanh-form GELU: branch-free, 1 transcendental
static __device__ __forceinline__ float gelu_fast(float z) {
  float y = 0.7978845608028654f * (z + 0.044715f * z * z * z);
  float e = __expf(2.f * y);
  float t = 1.f - 2.f / (1.f + e);
  return 0.5f * z * (1.f + t);
}

// checked: load 4 bf16 at column gj (4-aligned); zero-fill OOB
static __device__ __forceinline__ void ld4z(const unsigned short* rowptr,
                                            int gj, bool vrow, float* dst) {
  if (vrow && (unsigned)gj < 768u) {
    ushort4 u = *(const ushort4*)(rowptr + gj);
    dst[0] = bf2f(u.x); dst[1] = bf2f(u.y); dst[2] = bf2f(u.z); dst[3] = bf2f(u.w);
  } else {
    dst[0] = 0.f; dst[1] = 0.f; dst[2] = 0.f; dst[3] = 0.f;
  }
}

// checked window cols jc-1 .. jc+8 -> w10[0..9]  (k4 slow path)
static __device__ __forceinline__ void loadrow10(const unsigned short* rowptr,
                                                 bool vrow, int jc, float* w10) {
  float q[4];
  ld4z(rowptr, jc - 4, vrow, q);
  w10[0] = q[3];
  ld4z(rowptr, jc, vrow, q);
  w10[1] = q[0]; w10[2] = q[1]; w10[3] = q[2]; w10[4] = q[3];
  ld4z(rowptr, jc + 4, vrow, q);
  w10[5] = q[0]; w10[6] = q[1]; w10[7] = q[2]; w10[8] = q[3];
  ld4z(rowptr, jc + 8, vrow, q);
  w10[9] = q[0];
}

// unchecked fast window: 3 loads, 10 cvts; returns interior 8 raw bf16
static __device__ __forceinline__ bf16x8 ldrow10f(const unsigned short* p,
                                                  float* w) {
  ushort4 aa = *(const ushort4*)(p - 4);
  bf16x8 bb = *(const bf16x8*)(p);
  ushort4 cc = *(const ushort4*)(p + 8);
  w[0] = bf2f(aa.w);
#pragma unroll
  for (int e = 0; e < 8; ++e) w[1 + e] = bf2f((unsigned short)bb[e]);
  w[9] = bf2f(cc.x);
  return bb;
}

static __device__ __forceinline__ bf16x8 packrow(const float* w1) {
  bf16x8 r;
#pragma unroll
  for (int e = 0; e < 8; ++e) r[e] = (short)f2bf(w1[1 + e]);
  return r;
}

// 18-wide window cols jc-1 .. jc+16 (k3)
template <bool FAST>
static __device__ __forceinline__ void ldrow18(const unsigned short* rowp,
                                               bool vrow, int jc, float* W) {
  if (FAST) {
    ushort4 a = *(const ushort4*)(rowp + jc - 4);
    bf16x8 b0 = *(const bf16x8*)(rowp + jc);
    bf16x8 b1 = *(const bf16x8*)(rowp + jc + 8);
    ushort4 cc = *(const ushort4*)(rowp + jc + 16);
    W[0] = bf2f(a.w);
#pragma unroll
    for (int e = 0; e < 8; ++e) { W[1 + e] = bf2f((unsigned short)b0[e]);
                                  W[9 + e] = bf2f((unsigned short)b1[e]); }
    W[17] = bf2f(cc.x);
  } else {
    if (vrow) {
      W[0] = (jc >= 4) ? bf2f((*(const ushort4*)(rowp + jc - 4)).w) : 0.f;
      bf16x8 b0 = *(const bf16x8*)(rowp + jc);
      bf16x8 b1 = *(const bf16x8*)(rowp + jc + 8);
#pragma unroll
      for (int e = 0; e < 8; ++e) { W[1 + e] = bf2f((unsigned short)b0[e]);
                                    W[9 + e] = bf2f((unsigned short)b1[e]); }
      W[17] = (jc + 16 < 768) ? bf2f((*(const ushort4*)(rowp + jc + 16)).x) : 0.f;
    } else {
#pragma unroll
      for (int e = 0; e < 18; ++e) W[e] = 0.f;
    }
  }
}

// ---------------------------------------------------------------------------
// K1 (MFMA GEMM): a[m,d] = sum_e x[m,e]*W_sl[d,e] + b_sl[d] -> bf16
// Also zeroes the GN stats buffer (block 0) so no separate memset launch.
// ---------------------------------------------------------------------------
__global__ __launch_bounds__(256) void k1_proj(
    const float* __restrict__ x, const float* __restrict__ Wsl,
    const float* __restrict__ bsl, unsigned short* __restrict__ abf,
    float* __restrict__ stats) {
  __shared__ __align__(16) unsigned short xs[64 * 264];   // [row][k] bf16
  __shared__ __align__(16) unsigned short wsb[64 * 264];  // [d][k] bf16
  const int tid = threadIdx.x;
  const int bl = blockIdx.x;  // 0..23
  if (bl == 0 && tid < 128) stats[tid] = 0.f;
  const int lane = tid & 63, wv = tid >> 6;
  const int g = lane >> 4, l15 = lane & 15;

  f32x4 acc[4];
#pragma unroll
  for (int nt = 0; nt < 4; ++nt) acc[nt] = (f32x4){0.f, 0.f, 0.f, 0.f};

  for (int k0 = 0; k0 < 1024; k0 += 256) {
    __syncthreads();
#pragma unroll
    for (int it = 0; it < 16; ++it) {
      const int idx = (it * 256 + tid) * 4;
      const int row = idx >> 8, col = idx & 255;
      float4 xv = *(const float4*)&x[(size_t)(bl * 64 + row) * 1024 + k0 + col];
      *(ushort4*)&xs[row * 264 + col] =
          make_ushort4(f2bf(xv.x), f2bf(xv.y), f2bf(xv.z), f2bf(xv.w));
      float4 wv4 = *(const float4*)&Wsl[(size_t)row * 1024 + k0 + col];
      *(ushort4*)&wsb[row * 264 + col] =
          make_ushort4(f2bf(wv4.x), f2bf(wv4.y), f2bf(wv4.z), f2bf(wv4.w));
    }
    __syncthreads();
#pragma unroll
    for (int kk = 0; kk < 8; ++kk) {
      bf16x8 av = *(const bf16x8*)&xs[(wv * 16 + l15) * 264 + kk * 32 + g * 8];
#pragma unroll
      for (int nt = 0; nt < 4; ++nt) {
        bf16x8 bv =
            *(const bf16x8*)&wsb[(nt * 16 + l15) * 264 + kk * 32 + g * 8];
        acc[nt] = __builtin_amdgcn_mfma_f32_16x16x32_bf16(av, bv, acc[nt], 0, 0, 0);
      }
    }
  }

#pragma unroll
  for (int nt = 0; nt < 4; ++nt) {
    const int d = nt * 16 + l15;
    const float bo = bsl[d];
#pragma unroll
    for (int qq = 0; qq < 4; ++qq) {
      const int m = wv * 16 + g * 4 + qq;
      abf[(size_t)(bl * 64 + m) * 64 + d] = f2bf(acc[nt][qq] + bo);
    }
  }
}

// ---------------------------------------------------------------------------
// K2 v3 (MFMA, 2 i-rows/block): block = (b, i-pair, jblk). 512 thr (8 waves).
//   Waves 0-3 process i0, waves 4-7 process i1; Wop staged once for both.
// grid = 2*384*12 = 9216
// ---------------------------------------------------------------------------
__global__ __launch_bounds__(512) void k2_outer(
    const float* __restrict__ xpw, const unsigned short* __restrict__ abf,
    const float* __restrict__ Wop, const float* __restrict__ bop,
    const float* __restrict__ lnw, const float* __restrict__ lnb,
    unsigned short* __restrict__ xp) {
  __shared__ __align__(16) unsigned short Vt[2][64 * 72];  // [ih][c][d]
  __shared__ __align__(16) unsigned short Lt[2][64 * 72];  // [ih][c][j]
  __shared__ float ail[2][64];
  __shared__ float bopl[64], lnwl[64], lnbl[64];
  const int tid = threadIdx.x;
  const int bx = blockIdx.x;
  const int jblk = bx % 12;
  const int ip = (bx / 12) % 384;
  const int b = bx / (12 * 384);
  const int jb = jblk * 64;
  const int i0p = ip * 2;

  if (tid < 64) ail[0][tid] = bf2f(abf[(size_t)(b * 768 + i0p) * 64 + tid]);
  else if (tid < 128) bopl[tid - 64] = bop[tid - 64];
  else if (tid < 192) lnwl[tid - 128] = lnw[tid - 128];
  else if (tid < 256) lnbl[tid - 192] = lnb[tid - 192];
  else if (tid < 320)
    ail[1][tid - 256] = bf2f(abf[(size_t)(b * 768 + i0p + 1) * 64 + tid - 256]);
  __syncthreads();

  const int ih = tid >> 8, t8 = tid & 255;
  {  // build Vt for this half's i
    const int cV = t8 >> 2, d0 = (t8 & 3) << 4;
    const float4* wr = (const float4*)&Wop[cV * 64 + d0];
#pragma unroll
    for (int t = 0; t < 4; ++t) {
      float4 w4 = wr[t];
      ushort4 u = make_ushort4(f2bf(w4.x * ail[ih][d0 + 4 * t]),
                               f2bf(w4.y * ail[ih][d0 + 4 * t + 1]),
                               f2bf(w4.z * ail[ih][d0 + 4 * t + 2]),
                               f2bf(w4.w * ail[ih][d0 + 4 * t + 3]));
      *(ushort4*)&Vt[ih][cV * 72 + d0 + 4 * t] = u;
    }
  }
  __syncthreads();

  const int lane = tid & 63;
  const int w8 = tid >> 6;          // wave 0..7
  const int ihm = w8 >> 2, wv = w8 & 3;
  const int g = lane >> 4, l15 = lane & 15;
  f32x4 acc[4];
#pragma unroll
  for (int t = 0; t < 4; ++t) acc[t] = (f32x4){0.f, 0.f, 0.f, 0.f};

  const size_t arow = (size_t)(b * 768 + jb + wv * 16 + l15) * 64;
#pragma unroll
  for (int kk = 0; kk < 2; ++kk) {
    bf16x8 av = *(const bf16x8*)&abf[arow + kk * 32 + g * 8];
#pragma unroll
    for (int t = 0; t < 4; ++t) {
      bf16x8 bv = *(const bf16x8*)&Vt[ihm][(t * 16 + l15) * 72 + kk * 32 + g * 8];
      acc[t] = __builtin_amdgcn_mfma_f32_16x16x32_bf16(av, bv, acc[t], 0, 0, 0);
    }
  }

  float lw[4], lb[4], bo[4];
#pragma unroll
  for (int t = 0; t < 4; ++t) {
    lw[t] = lnwl[t * 16 + l15];
    lb[t] = lnbl[t * 16 + l15];
    bo[t] = bopl[t * 16 + l15];
  }
  float s1[4] = {0.f, 0.f, 0.f, 0.f}, s2[4] = {0.f, 0.f, 0.f, 0.f};
#pragma unroll
  for (int t = 0; t < 4; ++t)
#pragma unroll
    for (int q = 0; q < 4; ++q) {
      float v = acc[t][q] + bo[t];
      acc[t][q] = v;
      s1[q] += v;
      s2[q] += v * v;
    }
#pragma unroll
  for (int m = 1; m <= 8; m <<= 1)
#pragma unroll
    for (int q = 0; q < 4; ++q) {
      s1[q] += __shfl_xor(s1[q], m);
      s2[q] += __shfl_xor(s2[q], m);
    }
  float mean[4], rs[4];
#pragma unroll
  for (int q = 0; q < 4; ++q) {
    mean[q] = s1[q] * (1.f / 64.f);
    float var = s2[q] * (1.f / 64.f) - mean[q] * mean[q];
    rs[q] = rsqrtf(var + EPS_);
  }
#pragma unroll
  for (int t = 0; t < 4; ++t) {
    ushort4 u;
    unsigned short* up = (unsigned short*)&u;
#pragma unroll
    for (int q = 0; q < 4; ++q)
      up[q] = f2bf((acc[t][q] - mean[q]) * rs[q] * lw[t] + lb[t]);
    *(ushort4*)&Lt[ihm][(t * 16 + l15) * 72 + wv * 16 + g * 4] = u;
  }
  __syncthreads();

  {  // coalesced residual epilogue (each half handles its own i)
    const int ce = t8 >> 2, jq = t8 & 3;
    const int i = i0p + ih;
    const size_t gbase = ((size_t)(b * 64 + ce) * 768 + i) * 768 + jb + jq * 16;
    float vals[16];
#pragma unroll
    for (int h = 0; h < 2; ++h) {
      bf16x8 lv = *(const bf16x8*)&Lt[ih][ce * 72 + jq * 16 + h * 8];
#pragma unroll
      for (int e = 0; e < 8; ++e)
        vals[h * 8 + e] = bf2f((unsigned short)lv[e]);
    }
#pragma unroll
    for (int v4 = 0; v4 < 4; ++v4) {
      float4 xv = *(const float4*)&xpw[gbase + v4 * 4];
      ushort4 u = make_ushort4(f2bf(xv.x + vals[v4 * 4]),
                               f2bf(xv.y + vals[v4 * 4 + 1]),
                               f2bf(xv.z + vals[v4 * 4 + 2]),
                               f2bf(xv.w + vals[v4 * 4 + 3]));
      *(ushort4*)&xp[gbase + v4 * 4] = u;
    }
  }
}

// ---------------------------------------------------------------------------
// K3 v3: GN stats. 16-wide column windows, 4-row sub-slabs.
// thread = (col-chunk of 16 q:0..47, row-quarter half:0..7). 384 thr.
// grid = 2*64*24 = 3072
// ---------------------------------------------------------------------------
template <bool FAST>
static __device__ __forceinline__ void k3_body(const unsigned short* base,
                                               int i0, int jc, const float* w,
                                               float& s1, float& s2) {
  float W0[18], W1[18], W2[18];
  ldrow18<FAST>(base + (ptrdiff_t)(i0 - 1) * 768, i0 >= 1, jc, W0);
  ldrow18<FAST>(base + (ptrdiff_t)i0 * 768, true, jc, W1);
#pragma unroll
  for (int rr = 0; rr < 4; ++rr) {
    const int gi = i0 + rr + 1;
    ldrow18<FAST>(base + (ptrdiff_t)gi * 768, gi < 768, jc, W2);
#pragma unroll
    for (int k = 0; k < 16; ++k) {
      float h = w[0] * W0[k] + w[1] * W0[k + 1] + w[2] * W0[k + 2] +
                w[3] * W1[k] + w[4] * W1[k + 1] + w[5] * W1[k + 2] +
                w[6] * W2[k] + w[7] * W2[k + 1] + w[8] * W2[k + 2];
      s1 += h;
      s2 += h * h;
    }
#pragma unroll
    for (int t = 0; t < 18; ++t) { W0[t] = W1[t]; W1[t] = W2[t]; }
  }
}

__global__ __launch_bounds__(384) void k3_stats(
    const unsigned short* __restrict__ xp, const float* __restrict__ dww,
    float* __restrict__ stats) {
  const int tid = threadIdx.x;
  const int bx = blockIdx.x;
  const int it = bx % 24;
  const int c = (bx / 24) & 63;
  const int b = bx / (24 * 64);
  const int q = tid % 48;
  const int half = tid / 48;
  const int i0 = it * 32 + half * 4;
  const int jc = q * 16;
  const unsigned short* base = xp + (size_t)(b * 64 + c) * 768 * 768;
  float w[9];
#pragma unroll
  for (int k = 0; k < 9; ++k) w[k] = dww[c * 9 + k];

  float s1 = 0.f, s2 = 0.f;
  const bool fast = (i0 >= 1) && (i0 + 4 < 768) && (q >= 1) && (q <= 46);
  if (fast) k3_body<true>(base, i0, jc, w, s1, s2);
  else      k3_body<false>(base, i0, jc, w, s1, s2);

#pragma unroll
  for (int off = 32; off >= 1; off >>= 1) {
    s1 += __shfl_xor(s1, off);
    s2 += __shfl_xor(s2, off);
  }
  __shared__ float ws1[6], ws2[6];
  const int wid = tid >> 6;
  if ((tid & 63) == 0) { ws1[wid] = s1; ws2[wid] = s2; }
  __syncthreads();
  if (tid == 0) {
    float t1 = 0.f, t2 = 0.f;
#pragma unroll
    for (int k = 0; k < 6; ++k) { t1 += ws1[k]; t2 += ws2[k]; }
    const int grp = c >> 1;
    atomicAdd(&stats[(b * 32 + grp) * 2 + 0], t1);
    atomicAdd(&stats[(b * 32 + grp) * 2 + 1], t2);
  }
}

// ---------------------------------------------------------------------------
// K3b: per (b,c) GN scale/bias
// ---------------------------------------------------------------------------
__global__ void k3b_affine(const float* __restrict__ stats,
                           const float* __restrict__ gnw,
                           const float* __restrict__ gnb,
                           float* __restrict__ af) {
  int tid = threadIdx.x;
  if (tid >= 128) return;
  int b = tid >> 6, c = tid & 63, g = c >> 1;
  float s1 = stats[(b * 32 + g) * 2];
  float s2 = stats[(b * 32 + g) * 2 + 1];
  const float N = 2.f * 768.f * 768.f;
  float m = s1 / N;
  float v = s2 / N - m * m;
  float rs = rsqrtf(v + EPS_);
  float A = rs * gnw[c];
  af[(b * 64 + c) * 2] = A;
  af[(b * 64 + c) * 2 + 1] = gnb[c] - m * A;
}

// ---------------------------------------------------------------------------
// K4 phase-1 body: dwconv + GN affine + fast GELU -> gT; retains xp rows.
// ---------------------------------------------------------------------------
template <bool FAST>
static __device__ __forceinline__ void k4_phase1(
    const unsigned short* base, int i0, int jc, const float* w, float A,
    float Bv, int swzc, unsigned short* gT, int q, bf16x8* raw) {
  float w0[10], w1[10], w2[10];
  if (FAST) {
    ldrow10f(base + (size_t)(i0 - 1) * 768 + jc, w0);
    raw[0] = ldrow10f(base + (size_t)i0 * 768 + jc, w1);
  } else {
    loadrow10(base + (ptrdiff_t)(i0 - 1) * 768, i0 >= 1, jc, w0);
    loadrow10(base + (ptrdiff_t)i0 * 768, true, jc, w1);
    raw[0] = packrow(w1);
  }
#pragma unroll
  for (int r = 0; r < 4; ++r) {
    const int gi = i0 + r + 1;
    if (FAST) {
      bf16x8 rw = ldrow10f(base + (size_t)gi * 768 + jc, w2);
      if (r < 3) raw[r + 1] = rw;
    } else {
      loadrow10(base + (ptrdiff_t)gi * 768, gi < 768, jc, w2);
      if (r < 3) raw[r + 1] = packrow(w2);
    }
#pragma unroll
    for (int jj = 0; jj < 8; ++jj) {
      float h = w[0] * w0[jj] + w[1] * w0[jj + 1] + w[2] * w0[jj + 2] +
                w[3] * w1[jj] + w[4] * w1[jj + 1] + w[5] * w1[jj + 2] +
                w[6] * w2[jj] + w[7] * w2[jj + 1] + w[8] * w2[jj + 2];
      float z = A * h + Bv;
      const int p = r * 64 + q * 8 + jj;
      gT[p * 72 + swzc] = f2bf(gelu_fast(z));
    }
#pragma unroll
    for (int t = 0; t < 10; ++t) { w0[t] = w1[t]; w1[t] = w2[t]; }
  }
}

// ---------------------------------------------------------------------------
// K4: tile = 4 rows x 64 cols, all 64 ch. 512 threads, launch_bounds(512,4).
// grid = 2*192*12 = 4608
// ---------------------------------------------------------------------------
__global__ __launch_bounds__(512, 4) void k4_final(
    const unsigned short* __restrict__ xp, const float* __restrict__ af,
    const float* __restrict__ dww, const float* __restrict__ pww,
    const float* __restrict__ pwb, float* __restrict__ out) {
  __shared__ __align__(16) unsigned short gT[256 * 72];  // phase3: oT[64][264]
  __shared__ __align__(16) unsigned short pwF[64 * 72];  // [co][ci]
  __shared__ float dwl[576];
  __shared__ float afl[128];
  __shared__ float pwbl[64];
  const int tid = threadIdx.x;
  const int bx = blockIdx.x;
  const int jt = bx % 12;
  const int it = (bx / 12) % 192;
  const int b = bx / (12 * 192);
  const int i0 = it * 4, j0 = jt * 64;

  {  // stage pwF (bf16)
    const int co = tid >> 3, ci0 = (tid & 7) * 8;
    float4 f0 = *(const float4*)&pww[co * 64 + ci0];
    float4 f1 = *(const float4*)&pww[co * 64 + ci0 + 4];
    *(ushort4*)&pwF[co * 72 + ci0] =
        make_ushort4(f2bf(f0.x), f2bf(f0.y), f2bf(f0.z), f2bf(f0.w));
    *(ushort4*)&pwF[co * 72 + ci0 + 4] =
        make_ushort4(f2bf(f1.x), f2bf(f1.y), f2bf(f1.z), f2bf(f1.w));
  }
  for (int idx = tid; idx < 576; idx += 512) dwl[idx] = dww[idx];
  if (tid < 128) afl[tid] = af[b * 128 + tid];
  if (tid < 64) pwbl[tid] = pwb[tid];
  __syncthreads();

  const int c = tid >> 3, q = tid & 7;
  bf16x8 raw[4];
  {  // phase 1
    const float* w = &dwl[c * 9];
    const float A = afl[c * 2], Bv = afl[c * 2 + 1];
    const unsigned short* base = xp + (size_t)(b * 64 + c) * 768 * 768;
    const int jc = j0 + q * 8;
    const int swzc = (((c >> 3) ^ q) << 3) + (c & 7);
    if (it >= 1 && it <= 190 && jt >= 1 && jt <= 10)
      k4_phase1<true>(base, i0, jc, w, A, Bv, swzc, gT, q, raw);
    else
      k4_phase1<false>(base, i0, jc, w, A, Bv, swzc, gT, q, raw);
  }
  __syncthreads();

  // phase 2: MFMA 1x1.  D[pixel][co], A = gT (swizzled chunks), B = pwF
  const int lane = tid & 63, wv = tid >> 6;
  const int g = lane >> 4, l15 = lane & 15;
  f32x4 acc[2][4];
#pragma unroll
  for (int mt = 0; mt < 2; ++mt)
#pragma unroll
    for (int nt = 0; nt < 4; ++nt) acc[mt][nt] = (f32x4){0.f, 0.f, 0.f, 0.f};

#pragma unroll
  for (int kk = 0; kk < 2; ++kk) {
    const int p0 = wv * 32 + l15;
    const int p1 = p0 + 16;
    const int cc0 = (4 * kk + g) ^ ((p0 >> 3) & 7);
    const int cc1 = (4 * kk + g) ^ ((p1 >> 3) & 7);
    bf16x8 a0 = *(const bf16x8*)&gT[p0 * 72 + cc0 * 8];
    bf16x8 a1 = *(const bf16x8*)&gT[p1 * 72 + cc1 * 8];
#pragma unroll
    for (int nt = 0; nt < 4; ++nt) {
      bf16x8 bv = *(const bf16x8*)&pwF[(nt * 16 + l15) * 72 + kk * 32 + g * 8];
      acc[0][nt] = __builtin_amdgcn_mfma_f32_16x16x32_bf16(a0, bv, acc[0][nt], 0, 0, 0);
      acc[1][nt] = __builtin_amdgcn_mfma_f32_16x16x32_bf16(a1, bv, acc[1][nt], 0, 0, 0);
    }
  }
  __syncthreads();  // all gT reads done before oT overwrite

  // phase 2b: conv results -> oT[co][264] (bf16), reusing gT memory
  unsigned short* oT = gT;
#pragma unroll
  for (int mt = 0; mt < 2; ++mt) {
#pragma unroll
    for (int nt = 0; nt < 4; ++nt) {
      const int co = nt * 16 + l15;
      const int p0 = wv * 32 + mt * 16 + g * 4;
      f32x4 a = acc[mt][nt];
      ushort4 u = make_ushort4(f2bf(a[0]), f2bf(a[1]), f2bf(a[2]), f2bf(a[3]));
      *(ushort4*)&oT[co * 264 + p0] = u;
    }
  }
  __syncthreads();

  // phase 3: out = xp(reg) + conv(oT) + bias
  {
    const float pb = pwbl[c];
    const size_t rowbase = ((size_t)(b * 64 + c) * 768 + i0) * 768 + j0 + q * 8;
#pragma unroll
    for (int r = 0; r < 4; ++r) {
      bf16x8 cv = *(const bf16x8*)&oT[c * 264 + r * 64 + q * 8];
      bf16x8 xv = raw[r];
      float4 o0, o1;
      o0.x = bf2f((unsigned short)xv[0]) + bf2f((unsigned short)cv[0]) + pb;
      o0.y = bf2f((unsigned short)xv[1]) + bf2f((unsigned short)cv[1]) + pb;
      o0.z = bf2f((unsigned short)xv[2]) + bf2f((unsigned short)cv[2]) + pb;
      o0.w = bf2f((unsigned short)xv[3]) + bf2f((unsigned short)cv[3]) + pb;
      o1.x = bf2f((unsigned short)xv[4]) + bf2f((unsigned short)cv[4]) + pb;
      o1.y = bf2f((unsigned short)xv[5]) + bf2f((unsigned short)cv[5]) + pb;
      o1.z = bf2f((unsigned short)xv[6]) + bf2f((unsigned short)cv[6]) + pb;
      o1.w = bf2f((unsigned short)xv[7]) + bf2f((unsigned short)cv[7]) + pb;
      float* op = out + rowbase + (size_t)r * 768;
      *(float4*)op = o0;
      *(float4*)(op + 4) = o1;
    }
  }
}

// ---------------------------------------------------------------------------
extern "C" void kernel_launch(void* const* d_in, const int* in_sizes, int n_in,
                              void* d_out, int out_size, void* d_ws,
                              size_t ws_size, hipStream_t stream) {
  const float* x_pw = (const float*)d_in[0];
  const float* x    = (const float*)d_in[1];
  const float* Wsl  = (const float*)d_in[2];
  const float* bsl  = (const float*)d_in[3];
  const float* Wop  = (const float*)d_in[4];
  const float* bop  = (const float*)d_in[5];
  const float* lnw  = (const float*)d_in[6];
  const float* lnb  = (const float*)d_in[7];
  const float* dww  = (const float*)d_in[8];
  const float* gnw  = (const float*)d_in[9];
  const float* gnb  = (const float*)d_in[10];
  const float* pww  = (const float*)d_in[11];
  const float* pwb  = (const float*)d_in[12];
  float* out = (float*)d_out;

  char* ws = (char*)d_ws;
  unsigned short* a_bf = (unsigned short*)ws;             // 196608 B
  float* stats  = (float*)(ws + 196608);                  // 512 B
  float* affine = (float*)(ws + 197120);                  // 1024 B
  unsigned short* xpbuf = (unsigned short*)(ws + 262144); // 151 MB bf16

  k1_proj<<<24, 256, 0, stream>>>(x, Wsl, bsl, a_bf, stats);
  k2_outer<<<2 * 384 * 12, 512, 0, stream>>>(x_pw, a_bf, Wop, bop, lnw, lnb,
                                             xpbuf);
  k3_stats<<<2 * 64 * 24, 384, 0, stream>>>(xpbuf, dww, stats);
  k3b_affine<<<1, 128, 0, stream>>>(stats, gnw, gnb, affine);
  k4_final<<<2 * 192 * 12, 512, 0, stream>>>(xpbuf, affine, dww, pww, pwb, out);
}

// Round 8
// 441.646 us; speedup vs baseline: 1.0779x; 1.0779x over previous
//
#include <hip/hip_runtime.h>
#include <hip/hip_bf16.h>

#define EPS_ 1e-5f

typedef __attribute__((ext_vector_type(8))) short bf16x8;
typedef __attribute__((ext_vector_type(4))) float f32x4;

static __device__ __forceinline__ float bf2f(unsigned short u) {
  return __uint_as_float(((unsigned int)u) << 16);
}
static __device__ __forceinline__ unsigned short f2bf(float f) {
  unsigned int u = __float_as_uint(f);
  u += 0x7FFFu + ((u >> 16) & 1u);   // RNE
  return (unsigned short)(u >> 16);
}

// tanh-form GELU: branch-free, 1 transcendental
static __device__ __forceinline__ float gelu_fast(float z) {
  float y = 0.7978845608028654f * (z + 0.044715f * z * z * z);
  float e = __expf(2.f * y);
  float t = 1.f - 2.f / (1.f + e);
  return 0.5f * z * (1.f + t);
}

// checked: load 4 bf16 at column gj (4-aligned); zero-fill OOB
static __device__ __forceinline__ void ld4z(const unsigned short* rowptr,
                                            int gj, bool vrow, float* dst) {
  if (vrow && (unsigned)gj < 768u) {
    ushort4 u = *(const ushort4*)(rowptr + gj);
    dst[0] = bf2f(u.x); dst[1] = bf2f(u.y); dst[2] = bf2f(u.z); dst[3] = bf2f(u.w);
  } else {
    dst[0] = 0.f; dst[1] = 0.f; dst[2] = 0.f; dst[3] = 0.f;
  }
}

// checked window cols jc-1 .. jc+8 -> w10[0..9]
static __device__ __forceinline__ void loadrow10(const unsigned short* rowptr,
                                                 bool vrow, int jc, float* w10) {
  float q[4];
  ld4z(rowptr, jc - 4, vrow, q);
  w10[0] = q[3];
  ld4z(rowptr, jc, vrow, q);
  w10[1] = q[0]; w10[2] = q[1]; w10[3] = q[2]; w10[4] = q[3];
  ld4z(rowptr, jc + 4, vrow, q);
  w10[5] = q[0]; w10[6] = q[1]; w10[7] = q[2]; w10[8] = q[3];
  ld4z(rowptr, jc + 8, vrow, q);
  w10[9] = q[0];
}

static __device__ __forceinline__ bf16x8 packrow(const float* w1) {
  bf16x8 r;
#pragma unroll
  for (int e = 0; e < 8; ++e) r[e] = (short)f2bf(w1[1 + e]);
  return r;
}

// ---------------------------------------------------------------------------
// K1 (MFMA GEMM): a[m,d] = sum_e x[m,e]*W_sl[d,e] + b_sl[d] -> bf16
// Also zeroes the GN stats buffer (block 0).
// ---------------------------------------------------------------------------
__global__ __launch_bounds__(256) void k1_proj(
    const float* __restrict__ x, const float* __restrict__ Wsl,
    const float* __restrict__ bsl, unsigned short* __restrict__ abf,
    float* __restrict__ stats) {
  __shared__ __align__(16) unsigned short xs[64 * 264];   // [row][k] bf16
  __shared__ __align__(16) unsigned short wsb[64 * 264];  // [d][k] bf16
  const int tid = threadIdx.x;
  const int bl = blockIdx.x;  // 0..23
  if (bl == 0 && tid < 128) stats[tid] = 0.f;
  const int lane = tid & 63, wv = tid >> 6;
  const int g = lane >> 4, l15 = lane & 15;

  f32x4 acc[4];
#pragma unroll
  for (int nt = 0; nt < 4; ++nt) acc[nt] = (f32x4){0.f, 0.f, 0.f, 0.f};

  for (int k0 = 0; k0 < 1024; k0 += 256) {
    __syncthreads();
#pragma unroll
    for (int it = 0; it < 16; ++it) {
      const int idx = (it * 256 + tid) * 4;
      const int row = idx >> 8, col = idx & 255;
      float4 xv = *(const float4*)&x[(size_t)(bl * 64 + row) * 1024 + k0 + col];
      *(ushort4*)&xs[row * 264 + col] =
          make_ushort4(f2bf(xv.x), f2bf(xv.y), f2bf(xv.z), f2bf(xv.w));
      float4 wv4 = *(const float4*)&Wsl[(size_t)row * 1024 + k0 + col];
      *(ushort4*)&wsb[row * 264 + col] =
          make_ushort4(f2bf(wv4.x), f2bf(wv4.y), f2bf(wv4.z), f2bf(wv4.w));
    }
    __syncthreads();
#pragma unroll
    for (int kk = 0; kk < 8; ++kk) {
      bf16x8 av = *(const bf16x8*)&xs[(wv * 16 + l15) * 264 + kk * 32 + g * 8];
#pragma unroll
      for (int nt = 0; nt < 4; ++nt) {
        bf16x8 bv =
            *(const bf16x8*)&wsb[(nt * 16 + l15) * 264 + kk * 32 + g * 8];
        acc[nt] = __builtin_amdgcn_mfma_f32_16x16x32_bf16(av, bv, acc[nt], 0, 0, 0);
      }
    }
  }

#pragma unroll
  for (int nt = 0; nt < 4; ++nt) {
    const int d = nt * 16 + l15;
    const float bo = bsl[d];
#pragma unroll
    for (int qq = 0; qq < 4; ++qq) {
      const int m = wv * 16 + g * 4 + qq;
      abf[(size_t)(bl * 64 + m) * 64 + d] = f2bf(acc[nt][qq] + bo);
    }
  }
}

// ---------------------------------------------------------------------------
// K2 (MFMA, round-3 proven version): per (b,i, jblk of 64)
// grid = 2*768*12 = 18432, 256 threads
// ---------------------------------------------------------------------------
__global__ __launch_bounds__(256) void k2_outer(
    const float* __restrict__ xpw, const unsigned short* __restrict__ abf,
    const float* __restrict__ Wop, const float* __restrict__ bop,
    const float* __restrict__ lnw, const float* __restrict__ lnb,
    unsigned short* __restrict__ xp) {
  __shared__ __align__(16) unsigned short Vt[64 * 72];  // [c][d] bf16
  __shared__ __align__(16) unsigned short Lt[64 * 72];  // [c][j] bf16
  __shared__ float ail[64];
  __shared__ float bopl[64], lnwl[64], lnbl[64];
  const int tid = threadIdx.x;
  const int bx = blockIdx.x;
  const int jblk = bx % 12;
  const int i = (bx / 12) % 768;
  const int b = bx / (12 * 768);
  const int jb = jblk * 64;

  if (tid < 64) ail[tid] = bf2f(abf[(size_t)(b * 768 + i) * 64 + tid]);
  else if (tid < 128) bopl[tid - 64] = bop[tid - 64];
  else if (tid < 192) lnwl[tid - 128] = lnw[tid - 128];
  else lnbl[tid - 192] = lnb[tid - 192];
  __syncthreads();

  {  // build Vt
    const int c = tid >> 2, d0 = (tid & 3) << 4;
    const float4* wr = (const float4*)&Wop[c * 64 + d0];
#pragma unroll
    for (int t = 0; t < 4; ++t) {
      float4 w4 = wr[t];
      ushort4 u = make_ushort4(f2bf(w4.x * ail[d0 + 4 * t]),
                               f2bf(w4.y * ail[d0 + 4 * t + 1]),
                               f2bf(w4.z * ail[d0 + 4 * t + 2]),
                               f2bf(w4.w * ail[d0 + 4 * t + 3]));
      *(ushort4*)&Vt[c * 72 + d0 + 4 * t] = u;
    }
  }
  __syncthreads();

  const int lane = tid & 63, wv = tid >> 6;
  const int g = lane >> 4, l15 = lane & 15;
  f32x4 acc[4];
#pragma unroll
  for (int t = 0; t < 4; ++t) acc[t] = (f32x4){0.f, 0.f, 0.f, 0.f};

  const size_t arow = (size_t)(b * 768 + jb + wv * 16 + l15) * 64;
#pragma unroll
  for (int kk = 0; kk < 2; ++kk) {
    bf16x8 av = *(const bf16x8*)&abf[arow + kk * 32 + g * 8];
#pragma unroll
    for (int t = 0; t < 4; ++t) {
      bf16x8 bv = *(const bf16x8*)&Vt[(t * 16 + l15) * 72 + kk * 32 + g * 8];
      acc[t] = __builtin_amdgcn_mfma_f32_16x16x32_bf16(av, bv, acc[t], 0, 0, 0);
    }
  }

  float lw[4], lb[4], bo[4];
#pragma unroll
  for (int t = 0; t < 4; ++t) {
    lw[t] = lnwl[t * 16 + l15];
    lb[t] = lnbl[t * 16 + l15];
    bo[t] = bopl[t * 16 + l15];
  }
  float s1[4] = {0.f, 0.f, 0.f, 0.f}, s2[4] = {0.f, 0.f, 0.f, 0.f};
#pragma unroll
  for (int t = 0; t < 4; ++t)
#pragma unroll
    for (int q = 0; q < 4; ++q) {
      float v = acc[t][q] + bo[t];
      acc[t][q] = v;
      s1[q] += v;
      s2[q] += v * v;
    }
#pragma unroll
  for (int m = 1; m <= 8; m <<= 1)
#pragma unroll
    for (int q = 0; q < 4; ++q) {
      s1[q] += __shfl_xor(s1[q], m);
      s2[q] += __shfl_xor(s2[q], m);
    }
  float mean[4], rs[4];
#pragma unroll
  for (int q = 0; q < 4; ++q) {
    mean[q] = s1[q] * (1.f / 64.f);
    float var = s2[q] * (1.f / 64.f) - mean[q] * mean[q];
    rs[q] = rsqrtf(var + EPS_);
  }
#pragma unroll
  for (int t = 0; t < 4; ++t) {
    ushort4 u;
    unsigned short* up = (unsigned short*)&u;
#pragma unroll
    for (int q = 0; q < 4; ++q)
      up[q] = f2bf((acc[t][q] - mean[q]) * rs[q] * lw[t] + lb[t]);
    *(ushort4*)&Lt[(t * 16 + l15) * 72 + wv * 16 + g * 4] = u;
  }
  __syncthreads();

  {  // coalesced residual epilogue
    const int c = tid >> 2, jq = tid & 3;
    const size_t gbase = ((size_t)(b * 64 + c) * 768 + i) * 768 + jb + jq * 16;
    float vals[16];
#pragma unroll
    for (int h = 0; h < 2; ++h) {
      bf16x8 lv = *(const bf16x8*)&Lt[c * 72 + jq * 16 + h * 8];
#pragma unroll
      for (int e = 0; e < 8; ++e)
        vals[h * 8 + e] = bf2f((unsigned short)lv[e]);
    }
#pragma unroll
    for (int v4 = 0; v4 < 4; ++v4) {
      float4 xv = *(const float4*)&xpw[gbase + v4 * 4];
      ushort4 u = make_ushort4(f2bf(xv.x + vals[v4 * 4]),
                               f2bf(xv.y + vals[v4 * 4 + 1]),
                               f2bf(xv.z + vals[v4 * 4 + 2]),
                               f2bf(xv.w + vals[v4 * 4 + 3]));
      *(ushort4*)&xp[gbase + v4 * 4] = u;
    }
  }
}

// ---------------------------------------------------------------------------
// K3 (round-3 proven version): GN stats, 32-row slabs, 8-wide windows.
// grid = 2*64*24 = 3072, 384 threads
// ---------------------------------------------------------------------------
__global__ __launch_bounds__(384) void k3_stats(
    const unsigned short* __restrict__ xp, const float* __restrict__ dww,
    float* __restrict__ stats) {
  const int tid = threadIdx.x;
  const int bx = blockIdx.x;
  const int it = bx % 24;
  const int c = (bx / 24) & 63;
  const int b = bx / (24 * 64);
  const int q = tid % 96;
  const int half = tid / 96;
  const int i0 = it * 32 + half * 8;
  const int jc = q * 8;
  const unsigned short* base = xp + (size_t)(b * 64 + c) * 768 * 768;
  float w[9];
#pragma unroll
  for (int k = 0; k < 9; ++k) w[k] = dww[c * 9 + k];

  float w0[10], w1[10], w2[10];
  loadrow10(base + (ptrdiff_t)(i0 - 1) * 768, (i0 - 1) >= 0, jc, w0);
  loadrow10(base + (ptrdiff_t)i0 * 768, true, jc, w1);
  float s1 = 0.f, s2 = 0.f;
#pragma unroll
  for (int rr = 0; rr < 8; ++rr) {
    const int gi = i0 + rr + 1;
    loadrow10(base + (ptrdiff_t)gi * 768, gi < 768, jc, w2);
#pragma unroll
    for (int jj = 0; jj < 8; ++jj) {
      float h = w[0] * w0[jj] + w[1] * w0[jj + 1] + w[2] * w0[jj + 2] +
                w[3] * w1[jj] + w[4] * w1[jj + 1] + w[5] * w1[jj + 2] +
                w[6] * w2[jj] + w[7] * w2[jj + 1] + w[8] * w2[jj + 2];
      s1 += h;
      s2 += h * h;
    }
#pragma unroll
    for (int t = 0; t < 10; ++t) { w0[t] = w1[t]; w1[t] = w2[t]; }
  }
#pragma unroll
  for (int off = 32; off >= 1; off >>= 1) {
    s1 += __shfl_xor(s1, off);
    s2 += __shfl_xor(s2, off);
  }
  __shared__ float ws1[6], ws2[6];
  const int wid = tid >> 6;
  if ((tid & 63) == 0) { ws1[wid] = s1; ws2[wid] = s2; }
  __syncthreads();
  if (tid == 0) {
    float t1 = 0.f, t2 = 0.f;
#pragma unroll
    for (int k = 0; k < 6; ++k) { t1 += ws1[k]; t2 += ws2[k]; }
    const int grp = c >> 1;
    atomicAdd(&stats[(b * 32 + grp) * 2 + 0], t1);
    atomicAdd(&stats[(b * 32 + grp) * 2 + 1], t2);
  }
}

// ---------------------------------------------------------------------------
// K4 phase-1 fast path: preload ALL 18 row-vectors (6 rows x 3) into regs
// first (MLP=18), then convert + sliding-window conv. Retains xp rows.
// ---------------------------------------------------------------------------
static __device__ __forceinline__ void k4_phase1_fast(
    const unsigned short* base, int i0, int jc, const float* w, float A,
    float Bv, int swzc, unsigned short* gT, int q, bf16x8* raw) {
  ushort4 lf[6]; bf16x8 mid[6]; ushort4 rt[6];
  {
    const unsigned short* rp = base + (ptrdiff_t)(i0 - 1) * 768 + jc;
#pragma unroll
    for (int r = 0; r < 6; ++r) {
      lf[r] = *(const ushort4*)(rp - 4);
      mid[r] = *(const bf16x8*)(rp);
      rt[r] = *(const ushort4*)(rp + 8);
      rp += 768;
    }
  }
#pragma unroll
  for (int r = 0; r < 3; ++r) raw[r] = mid[r + 1];
  raw[3] = mid[4];

  float w0[10], w1[10], w2[10];
#pragma unroll
  for (int e = 0; e < 8; ++e) { w0[1 + e] = bf2f((unsigned short)mid[0][e]);
                                w1[1 + e] = bf2f((unsigned short)mid[1][e]); }
  w0[0] = bf2f(lf[0].w); w0[9] = bf2f(rt[0].x);
  w1[0] = bf2f(lf[1].w); w1[9] = bf2f(rt[1].x);
#pragma unroll
  for (int r = 0; r < 4; ++r) {
    w2[0] = bf2f(lf[r + 2].w);
#pragma unroll
    for (int e = 0; e < 8; ++e) w2[1 + e] = bf2f((unsigned short)mid[r + 2][e]);
    w2[9] = bf2f(rt[r + 2].x);
#pragma unroll
    for (int jj = 0; jj < 8; ++jj) {
      float h = w[0] * w0[jj] + w[1] * w0[jj + 1] + w[2] * w0[jj + 2] +
                w[3] * w1[jj] + w[4] * w1[jj + 1] + w[5] * w1[jj + 2] +
                w[6] * w2[jj] + w[7] * w2[jj + 1] + w[8] * w2[jj + 2];
      float z = A * h + Bv;
      const int p = r * 64 + q * 8 + jj;
      gT[p * 72 + swzc] = f2bf(gelu_fast(z));
    }
#pragma unroll
    for (int t = 0; t < 10; ++t) { w0[t] = w1[t]; w1[t] = w2[t]; }
  }
}

// slow (boundary) path: checked loads
static __device__ __forceinline__ void k4_phase1_slow(
    const unsigned short* base, int i0, int jc, const float* w, float A,
    float Bv, int swzc, unsigned short* gT, int q, bf16x8* raw) {
  float w0[10], w1[10], w2[10];
  loadrow10(base + (ptrdiff_t)(i0 - 1) * 768, i0 >= 1, jc, w0);
  loadrow10(base + (ptrdiff_t)i0 * 768, true, jc, w1);
  raw[0] = packrow(w1);
#pragma unroll
  for (int r = 0; r < 4; ++r) {
    const int gi = i0 + r + 1;
    loadrow10(base + (ptrdiff_t)gi * 768, gi < 768, jc, w2);
    if (r < 3) raw[r + 1] = packrow(w2);
#pragma unroll
    for (int jj = 0; jj < 8; ++jj) {
      float h = w[0] * w0[jj] + w[1] * w0[jj + 1] + w[2] * w0[jj + 2] +
                w[3] * w1[jj] + w[4] * w1[jj + 1] + w[5] * w1[jj + 2] +
                w[6] * w2[jj] + w[7] * w2[jj + 1] + w[8] * w2[jj + 2];
      float z = A * h + Bv;
      const int p = r * 64 + q * 8 + jj;
      gT[p * 72 + swzc] = f2bf(gelu_fast(z));
    }
#pragma unroll
    for (int t = 0; t < 10; ++t) { w0[t] = w1[t]; w1[t] = w2[t]; }
  }
}

// ---------------------------------------------------------------------------
// K4: tile = 4 rows x 64 cols, all 64 ch. 512 threads, launch_bounds(512,4).
// Computes GN affine per block from stats (k3b folded in).
// grid = 2*192*12 = 4608
// ---------------------------------------------------------------------------
__global__ __launch_bounds__(512, 4) void k4_final(
    const unsigned short* __restrict__ xp, const float* __restrict__ stats,
    const float* __restrict__ gnw, const float* __restrict__ gnb,
    const float* __restrict__ dww, const float* __restrict__ pww,
    const float* __restrict__ pwb, float* __restrict__ out) {
  __shared__ __align__(16) unsigned short gT[256 * 72];  // phase3: oT[64][264]
  __shared__ __align__(16) unsigned short pwF[64 * 72];  // [co][ci]
  __shared__ float dwl[576];
  __shared__ float afl[128];
  __shared__ float pwbl[64];
  const int tid = threadIdx.x;
  const int bx = blockIdx.x;
  const int jt = bx % 12;
  const int it = (bx / 12) % 192;
  const int b = bx / (12 * 192);
  const int i0 = it * 4, j0 = jt * 64;

  {  // stage pwF (bf16)
    const int co = tid >> 3, ci0 = (tid & 7) * 8;
    float4 f0 = *(const float4*)&pww[co * 64 + ci0];
    float4 f1 = *(const float4*)&pww[co * 64 + ci0 + 4];
    *(ushort4*)&pwF[co * 72 + ci0] =
        make_ushort4(f2bf(f0.x), f2bf(f0.y), f2bf(f0.z), f2bf(f0.w));
    *(ushort4*)&pwF[co * 72 + ci0 + 4] =
        make_ushort4(f2bf(f1.x), f2bf(f1.y), f2bf(f1.z), f2bf(f1.w));
  }
  for (int idx = tid; idx < 576; idx += 512) dwl[idx] = dww[idx];
  if (tid < 64) {  // GN affine per channel (k3b folded)
    const int cc = tid, grp = cc >> 1;
    const float s1 = stats[(b * 32 + grp) * 2];
    const float s2 = stats[(b * 32 + grp) * 2 + 1];
    const float N = 2.f * 768.f * 768.f;
    const float m = s1 / N;
    const float v = s2 / N - m * m;
    const float rsg = rsqrtf(v + EPS_);
    const float A = rsg * gnw[cc];
    afl[cc * 2] = A;
    afl[cc * 2 + 1] = gnb[cc] - m * A;
    pwbl[cc] = pwb[cc];
  }
  __syncthreads();

  const int c = tid >> 3, q = tid & 7;
  bf16x8 raw[4];
  {  // phase 1
    const float* w = &dwl[c * 9];
    const float A = afl[c * 2], Bv = afl[c * 2 + 1];
    const unsigned short* base = xp + (size_t)(b * 64 + c) * 768 * 768;
    const int jc = j0 + q * 8;
    const int swzc = (((c >> 3) ^ q) << 3) + (c & 7);
    if (it >= 1 && it <= 190 && jt >= 1 && jt <= 10)
      k4_phase1_fast(base, i0, jc, w, A, Bv, swzc, gT, q, raw);
    else
      k4_phase1_slow(base, i0, jc, w, A, Bv, swzc, gT, q, raw);
  }
  __syncthreads();

  // phase 2: MFMA 1x1.  D[pixel][co], A = gT (swizzled chunks), B = pwF
  const int lane = tid & 63, wv = tid >> 6;
  const int g = lane >> 4, l15 = lane & 15;
  f32x4 acc[2][4];
#pragma unroll
  for (int mt = 0; mt < 2; ++mt)
#pragma unroll
    for (int nt = 0; nt < 4; ++nt) acc[mt][nt] = (f32x4){0.f, 0.f, 0.f, 0.f};

#pragma unroll
  for (int kk = 0; kk < 2; ++kk) {
    const int p0 = wv * 32 + l15;
    const int p1 = p0 + 16;
    const int cc0 = (4 * kk + g) ^ ((p0 >> 3) & 7);
    const int cc1 = (4 * kk + g) ^ ((p1 >> 3) & 7);
    bf16x8 a0 = *(const bf16x8*)&gT[p0 * 72 + cc0 * 8];
    bf16x8 a1 = *(const bf16x8*)&gT[p1 * 72 + cc1 * 8];
#pragma unroll
    for (int nt = 0; nt < 4; ++nt) {
      bf16x8 bv = *(const bf16x8*)&pwF[(nt * 16 + l15) * 72 + kk * 32 + g * 8];
      acc[0][nt] = __builtin_amdgcn_mfma_f32_16x16x32_bf16(a0, bv, acc[0][nt], 0, 0, 0);
      acc[1][nt] = __builtin_amdgcn_mfma_f32_16x16x32_bf16(a1, bv, acc[1][nt], 0, 0, 0);
    }
  }
  __syncthreads();  // all gT reads done before oT overwrite

  // phase 2b: conv results -> oT[co][264] (bf16), reusing gT memory
  unsigned short* oT = gT;
#pragma unroll
  for (int mt = 0; mt < 2; ++mt) {
#pragma unroll
    for (int nt = 0; nt < 4; ++nt) {
      const int co = nt * 16 + l15;
      const int p0 = wv * 32 + mt * 16 + g * 4;
      f32x4 a = acc[mt][nt];
      ushort4 u = make_ushort4(f2bf(a[0]), f2bf(a[1]), f2bf(a[2]), f2bf(a[3]));
      *(ushort4*)&oT[co * 264 + p0] = u;
    }
  }
  __syncthreads();

  // phase 3: out = xp(reg) + conv(oT) + bias
  {
    const float pb = pwbl[c];
    const size_t rowbase = ((size_t)(b * 64 + c) * 768 + i0) * 768 + j0 + q * 8;
#pragma unroll
    for (int r = 0; r < 4; ++r) {
      bf16x8 cv = *(const bf16x8*)&oT[c * 264 + r * 64 + q * 8];
      bf16x8 xv = raw[r];
      float4 o0, o1;
      o0.x = bf2f((unsigned short)xv[0]) + bf2f((unsigned short)cv[0]) + pb;
      o0.y = bf2f((unsigned short)xv[1]) + bf2f((unsigned short)cv[1]) + pb;
      o0.z = bf2f((unsigned short)xv[2]) + bf2f((unsigned short)cv[2]) + pb;
      o0.w = bf2f((unsigned short)xv[3]) + bf2f((unsigned short)cv[3]) + pb;
      o1.x = bf2f((unsigned short)xv[4]) + bf2f((unsigned short)cv[4]) + pb;
      o1.y = bf2f((unsigned short)xv[5]) + bf2f((unsigned short)cv[5]) + pb;
      o1.z = bf2f((unsigned short)xv[6]) + bf2f((unsigned short)cv[6]) + pb;
      o1.w = bf2f((unsigned short)xv[7]) + bf2f((unsigned short)cv[7]) + pb;
      float* op = out + rowbase + (size_t)r * 768;
      *(float4*)op = o0;
      *(float4*)(op + 4) = o1;
    }
  }
}

// ---------------------------------------------------------------------------
extern "C" void kernel_launch(void* const* d_in, const int* in_sizes, int n_in,
                              void* d_out, int out_size, void* d_ws,
                              size_t ws_size, hipStream_t stream) {
  const float* x_pw = (const float*)d_in[0];
  const float* x    = (const float*)d_in[1];
  const float* Wsl  = (const float*)d_in[2];
  const float* bsl  = (const float*)d_in[3];
  const float* Wop  = (const float*)d_in[4];
  const float* bop  = (const float*)d_in[5];
  const float* lnw  = (const float*)d_in[6];
  const float* lnb  = (const float*)d_in[7];
  const float* dww  = (const float*)d_in[8];
  const float* gnw  = (const float*)d_in[9];
  const float* gnb  = (const float*)d_in[10];
  const float* pww  = (const float*)d_in[11];
  const float* pwb  = (const float*)d_in[12];
  float* out = (float*)d_out;

  char* ws = (char*)d_ws;
  unsigned short* a_bf = (unsigned short*)ws;             // 196608 B
  float* stats  = (float*)(ws + 196608);                  // 512 B
  unsigned short* xpbuf = (unsigned short*)(ws + 262144); // 151 MB bf16

  k1_proj<<<24, 256, 0, stream>>>(x, Wsl, bsl, a_bf, stats);
  k2_outer<<<2 * 768 * 12, 256, 0, stream>>>(x_pw, a_bf, Wop, bop, lnw, lnb,
                                             xpbuf);
  k3_stats<<<2 * 64 * 24, 384, 0, stream>>>(xpbuf, dww, stats);
  k4_final<<<2 * 192 * 12, 512, 0, stream>>>(xpbuf, stats, gnw, gnb, dww, pww,
                                             pwb, out);
}

// Round 10
// 406.632 us; speedup vs baseline: 1.1707x; 1.0861x over previous
//
#include <hip/hip_runtime.h>
#include <hip/hip_bf16.h>

#define EPS_ 1e-5f

typedef __attribute__((ext_vector_type(8))) short bf16x8;
typedef __attribute__((ext_vector_type(4))) float f32x4;

static __device__ __forceinline__ float bf2f(unsigned short u) {
  return __uint_as_float(((unsigned int)u) << 16);
}
static __device__ __forceinline__ unsigned short f2bf(float f) {
  unsigned int u = __float_as_uint(f);
  u += 0x7FFFu + ((u >> 16) & 1u);   // RNE
  return (unsigned short)(u >> 16);
}

// tanh-form GELU: branch-free, 1 transcendental
static __device__ __forceinline__ float gelu_fast(float z) {
  float y = 0.7978845608028654f * (z + 0.044715f * z * z * z);
  float e = __expf(2.f * y);
  float t = 1.f - 2.f / (1.f + e);
  return 0.5f * z * (1.f + t);
}

// checked: load 4 bf16 at column gj (4-aligned); zero-fill OOB
static __device__ __forceinline__ void ld4z(const unsigned short* rowptr,
                                            int gj, bool vrow, float* dst) {
  if (vrow && (unsigned)gj < 768u) {
    ushort4 u = *(const ushort4*)(rowptr + gj);
    dst[0] = bf2f(u.x); dst[1] = bf2f(u.y); dst[2] = bf2f(u.z); dst[3] = bf2f(u.w);
  } else {
    dst[0] = 0.f; dst[1] = 0.f; dst[2] = 0.f; dst[3] = 0.f;
  }
}

// checked window cols jc-1 .. jc+8 -> w10[0..9]
static __device__ __forceinline__ void loadrow10(const unsigned short* rowptr,
                                                 bool vrow, int jc, float* w10) {
  float q[4];
  ld4z(rowptr, jc - 4, vrow, q);
  w10[0] = q[3];
  ld4z(rowptr, jc, vrow, q);
  w10[1] = q[0]; w10[2] = q[1]; w10[3] = q[2]; w10[4] = q[3];
  ld4z(rowptr, jc + 4, vrow, q);
  w10[5] = q[0]; w10[6] = q[1]; w10[7] = q[2]; w10[8] = q[3];
  ld4z(rowptr, jc + 8, vrow, q);
  w10[9] = q[0];
}

static __device__ __forceinline__ bf16x8 packrow(const float* w1) {
  bf16x8 r;
#pragma unroll
  for (int e = 0; e < 8; ++e) r[e] = (short)f2bf(w1[1 + e]);
  return r;
}

// ---------------------------------------------------------------------------
// K1 (MFMA GEMM): a[m,d] = sum_e x[m,e]*W_sl[d,e] + b_sl[d] -> bf16
// Also zeroes the GN stats buffer (block 0).
// ---------------------------------------------------------------------------
__global__ __launch_bounds__(256) void k1_proj(
    const float* __restrict__ x, const float* __restrict__ Wsl,
    const float* __restrict__ bsl, unsigned short* __restrict__ abf,
    float* __restrict__ stats) {
  __shared__ __align__(16) unsigned short xs[64 * 264];   // [row][k] bf16
  __shared__ __align__(16) unsigned short wsb[64 * 264];  // [d][k] bf16
  const int tid = threadIdx.x;
  const int bl = blockIdx.x;  // 0..23
  if (bl == 0 && tid < 128) stats[tid] = 0.f;
  const int lane = tid & 63, wv = tid >> 6;
  const int g = lane >> 4, l15 = lane & 15;

  f32x4 acc[4];
#pragma unroll
  for (int nt = 0; nt < 4; ++nt) acc[nt] = (f32x4){0.f, 0.f, 0.f, 0.f};

  for (int k0 = 0; k0 < 1024; k0 += 256) {
    __syncthreads();
#pragma unroll
    for (int it = 0; it < 16; ++it) {
      const int idx = (it * 256 + tid) * 4;
      const int row = idx >> 8, col = idx & 255;
      float4 xv = *(const float4*)&x[(size_t)(bl * 64 + row) * 1024 + k0 + col];
      *(ushort4*)&xs[row * 264 + col] =
          make_ushort4(f2bf(xv.x), f2bf(xv.y), f2bf(xv.z), f2bf(xv.w));
      float4 wv4 = *(const float4*)&Wsl[(size_t)row * 1024 + k0 + col];
      *(ushort4*)&wsb[row * 264 + col] =
          make_ushort4(f2bf(wv4.x), f2bf(wv4.y), f2bf(wv4.z), f2bf(wv4.w));
    }
    __syncthreads();
#pragma unroll
    for (int kk = 0; kk < 8; ++kk) {
      bf16x8 av = *(const bf16x8*)&xs[(wv * 16 + l15) * 264 + kk * 32 + g * 8];
#pragma unroll
      for (int nt = 0; nt < 4; ++nt) {
        bf16x8 bv =
            *(const bf16x8*)&wsb[(nt * 16 + l15) * 264 + kk * 32 + g * 8];
        acc[nt] = __builtin_amdgcn_mfma_f32_16x16x32_bf16(av, bv, acc[nt], 0, 0, 0);
      }
    }
  }

#pragma unroll
  for (int nt = 0; nt < 4; ++nt) {
    const int d = nt * 16 + l15;
    const float bo = bsl[d];
#pragma unroll
    for (int qq = 0; qq < 4; ++qq) {
      const int m = wv * 16 + g * 4 + qq;
      abf[(size_t)(bl * 64 + m) * 64 + d] = f2bf(acc[nt][qq] + bo);
    }
  }
}

// ---------------------------------------------------------------------------
// K2 (MFMA): per (b,i, jblk of 64). Non-temporal x_pw loads (read-once) so
// xp stays resident in L2/L3 for k3/k4.
// grid = 2*768*12 = 18432, 256 threads
// ---------------------------------------------------------------------------
__global__ __launch_bounds__(256) void k2_outer(
    const float* __restrict__ xpw, const unsigned short* __restrict__ abf,
    const float* __restrict__ Wop, const float* __restrict__ bop,
    const float* __restrict__ lnw, const float* __restrict__ lnb,
    unsigned short* __restrict__ xp) {
  __shared__ __align__(16) unsigned short Vt[64 * 72];  // [c][d] bf16
  __shared__ __align__(16) unsigned short Lt[64 * 72];  // [c][j] bf16
  __shared__ float ail[64];
  __shared__ float bopl[64], lnwl[64], lnbl[64];
  const int tid = threadIdx.x;
  const int bx = blockIdx.x;
  const int jblk = bx % 12;
  const int i = (bx / 12) % 768;
  const int b = bx / (12 * 768);
  const int jb = jblk * 64;

  if (tid < 64) ail[tid] = bf2f(abf[(size_t)(b * 768 + i) * 64 + tid]);
  else if (tid < 128) bopl[tid - 64] = bop[tid - 64];
  else if (tid < 192) lnwl[tid - 128] = lnw[tid - 128];
  else lnbl[tid - 192] = lnb[tid - 192];
  __syncthreads();

  {  // build Vt
    const int c = tid >> 2, d0 = (tid & 3) << 4;
    const float4* wr = (const float4*)&Wop[c * 64 + d0];
#pragma unroll
    for (int t = 0; t < 4; ++t) {
      float4 w4 = wr[t];
      ushort4 u = make_ushort4(f2bf(w4.x * ail[d0 + 4 * t]),
                               f2bf(w4.y * ail[d0 + 4 * t + 1]),
                               f2bf(w4.z * ail[d0 + 4 * t + 2]),
                               f2bf(w4.w * ail[d0 + 4 * t + 3]));
      *(ushort4*)&Vt[c * 72 + d0 + 4 * t] = u;
    }
  }
  __syncthreads();

  const int lane = tid & 63, wv = tid >> 6;
  const int g = lane >> 4, l15 = lane & 15;
  f32x4 acc[4];
#pragma unroll
  for (int t = 0; t < 4; ++t) acc[t] = (f32x4){0.f, 0.f, 0.f, 0.f};

  const size_t arow = (size_t)(b * 768 + jb + wv * 16 + l15) * 64;
#pragma unroll
  for (int kk = 0; kk < 2; ++kk) {
    bf16x8 av = *(const bf16x8*)&abf[arow + kk * 32 + g * 8];
#pragma unroll
    for (int t = 0; t < 4; ++t) {
      bf16x8 bv = *(const bf16x8*)&Vt[(t * 16 + l15) * 72 + kk * 32 + g * 8];
      acc[t] = __builtin_amdgcn_mfma_f32_16x16x32_bf16(av, bv, acc[t], 0, 0, 0);
    }
  }

  float lw[4], lb[4], bo[4];
#pragma unroll
  for (int t = 0; t < 4; ++t) {
    lw[t] = lnwl[t * 16 + l15];
    lb[t] = lnbl[t * 16 + l15];
    bo[t] = bopl[t * 16 + l15];
  }
  float s1[4] = {0.f, 0.f, 0.f, 0.f}, s2[4] = {0.f, 0.f, 0.f, 0.f};
#pragma unroll
  for (int t = 0; t < 4; ++t)
#pragma unroll
    for (int q = 0; q < 4; ++q) {
      float v = acc[t][q] + bo[t];
      acc[t][q] = v;
      s1[q] += v;
      s2[q] += v * v;
    }
#pragma unroll
  for (int m = 1; m <= 8; m <<= 1)
#pragma unroll
    for (int q = 0; q < 4; ++q) {
      s1[q] += __shfl_xor(s1[q], m);
      s2[q] += __shfl_xor(s2[q], m);
    }
  float mean[4], rs[4];
#pragma unroll
  for (int q = 0; q < 4; ++q) {
    mean[q] = s1[q] * (1.f / 64.f);
    float var = s2[q] * (1.f / 64.f) - mean[q] * mean[q];
    rs[q] = rsqrtf(var + EPS_);
  }
#pragma unroll
  for (int t = 0; t < 4; ++t) {
    ushort4 u;
    unsigned short* up = (unsigned short*)&u;
#pragma unroll
    for (int q = 0; q < 4; ++q)
      up[q] = f2bf((acc[t][q] - mean[q]) * rs[q] * lw[t] + lb[t]);
    *(ushort4*)&Lt[(t * 16 + l15) * 72 + wv * 16 + g * 4] = u;
  }
  __syncthreads();

  {  // coalesced residual epilogue; x_pw via non-temporal loads
    const int c = tid >> 2, jq = tid & 3;
    const size_t gbase = ((size_t)(b * 64 + c) * 768 + i) * 768 + jb + jq * 16;
    float vals[16];
#pragma unroll
    for (int h = 0; h < 2; ++h) {
      bf16x8 lv = *(const bf16x8*)&Lt[c * 72 + jq * 16 + h * 8];
#pragma unroll
      for (int e = 0; e < 8; ++e)
        vals[h * 8 + e] = bf2f((unsigned short)lv[e]);
    }
#pragma unroll
    for (int v4 = 0; v4 < 4; ++v4) {
      f32x4 xv = __builtin_nontemporal_load(
          reinterpret_cast<const f32x4*>(&xpw[gbase + v4 * 4]));
      ushort4 u = make_ushort4(f2bf(xv[0] + vals[v4 * 4]),
                               f2bf(xv[1] + vals[v4 * 4 + 1]),
                               f2bf(xv[2] + vals[v4 * 4 + 2]),
                               f2bf(xv[3] + vals[v4 * 4 + 3]));
      *(ushort4*)&xp[gbase + v4 * 4] = u;
    }
  }
}

// ---------------------------------------------------------------------------
// K3: GN stats, 32-row slabs. XCD-chunked swizzle (grid 3072 = 8*384) so
// adjacent it-slabs (shared halo rows, L3-hot xp) co-reside per XCD.
// ---------------------------------------------------------------------------
__global__ __launch_bounds__(384) void k3_stats(
    const unsigned short* __restrict__ xp, const float* __restrict__ dww,
    float* __restrict__ stats) {
  const int tid = threadIdx.x;
  const int bx0 = blockIdx.x;
  const int bx = (bx0 & 7) * 384 + (bx0 >> 3);   // bijective: 3072 = 8*384
  const int it = bx % 24;
  const int c = (bx / 24) & 63;
  const int b = bx / (24 * 64);
  const int q = tid % 96;
  const int half = tid / 96;
  const int i0 = it * 32 + half * 8;
  const int jc = q * 8;
  const unsigned short* base = xp + (size_t)(b * 64 + c) * 768 * 768;
  float w[9];
#pragma unroll
  for (int k = 0; k < 9; ++k) w[k] = dww[c * 9 + k];

  float w0[10], w1[10], w2[10];
  loadrow10(base + (ptrdiff_t)(i0 - 1) * 768, (i0 - 1) >= 0, jc, w0);
  loadrow10(base + (ptrdiff_t)i0 * 768, true, jc, w1);
  float s1 = 0.f, s2 = 0.f;
#pragma unroll
  for (int rr = 0; rr < 8; ++rr) {
    const int gi = i0 + rr + 1;
    loadrow10(base + (ptrdiff_t)gi * 768, gi < 768, jc, w2);
#pragma unroll
    for (int jj = 0; jj < 8; ++jj) {
      float h = w[0] * w0[jj] + w[1] * w0[jj + 1] + w[2] * w0[jj + 2] +
                w[3] * w1[jj] + w[4] * w1[jj + 1] + w[5] * w1[jj + 2] +
                w[6] * w2[jj] + w[7] * w2[jj + 1] + w[8] * w2[jj + 2];
      s1 += h;
      s2 += h * h;
    }
#pragma unroll
    for (int t = 0; t < 10; ++t) { w0[t] = w1[t]; w1[t] = w2[t]; }
  }
#pragma unroll
  for (int off = 32; off >= 1; off >>= 1) {
    s1 += __shfl_xor(s1, off);
    s2 += __shfl_xor(s2, off);
  }
  __shared__ float ws1[6], ws2[6];
  const int wid = tid >> 6;
  if ((tid & 63) == 0) { ws1[wid] = s1; ws2[wid] = s2; }
  __syncthreads();
  if (tid == 0) {
    float t1 = 0.f, t2 = 0.f;
#pragma unroll
    for (int k = 0; k < 6; ++k) { t1 += ws1[k]; t2 += ws2[k]; }
    const int grp = c >> 1;
    atomicAdd(&stats[(b * 32 + grp) * 2 + 0], t1);
    atomicAdd(&stats[(b * 32 + grp) * 2 + 1], t2);
  }
}

// ---------------------------------------------------------------------------
// K4 phase-1 fast path: preload ALL 18 row-vectors into regs (MLP=18),
// then convert + sliding-window conv. Retains xp rows.
// ---------------------------------------------------------------------------
static __device__ __forceinline__ void k4_phase1_fast(
    const unsigned short* base, int i0, int jc, const float* w, float A,
    float Bv, int swzc, unsigned short* gT, int q, bf16x8* raw) {
  ushort4 lf[6]; bf16x8 mid[6]; ushort4 rt[6];
  {
    const unsigned short* rp = base + (ptrdiff_t)(i0 - 1) * 768 + jc;
#pragma unroll
    for (int r = 0; r < 6; ++r) {
      lf[r] = *(const ushort4*)(rp - 4);
      mid[r] = *(const bf16x8*)(rp);
      rt[r] = *(const ushort4*)(rp + 8);
      rp += 768;
    }
  }
#pragma unroll
  for (int r = 0; r < 3; ++r) raw[r] = mid[r + 1];
  raw[3] = mid[4];

  float w0[10], w1[10], w2[10];
#pragma unroll
  for (int e = 0; e < 8; ++e) { w0[1 + e] = bf2f((unsigned short)mid[0][e]);
                                w1[1 + e] = bf2f((unsigned short)mid[1][e]); }
  w0[0] = bf2f(lf[0].w); w0[9] = bf2f(rt[0].x);
  w1[0] = bf2f(lf[1].w); w1[9] = bf2f(rt[1].x);
#pragma unroll
  for (int r = 0; r < 4; ++r) {
    w2[0] = bf2f(lf[r + 2].w);
#pragma unroll
    for (int e = 0; e < 8; ++e) w2[1 + e] = bf2f((unsigned short)mid[r + 2][e]);
    w2[9] = bf2f(rt[r + 2].x);
#pragma unroll
    for (int jj = 0; jj < 8; ++jj) {
      float h = w[0] * w0[jj] + w[1] * w0[jj + 1] + w[2] * w0[jj + 2] +
                w[3] * w1[jj] + w[4] * w1[jj + 1] + w[5] * w1[jj + 2] +
                w[6] * w2[jj] + w[7] * w2[jj + 1] + w[8] * w2[jj + 2];
      float z = A * h + Bv;
      const int p = r * 64 + q * 8 + jj;
      gT[p * 72 + swzc] = f2bf(gelu_fast(z));
    }
#pragma unroll
    for (int t = 0; t < 10; ++t) { w0[t] = w1[t]; w1[t] = w2[t]; }
  }
}

// slow (boundary) path: checked loads
static __device__ __forceinline__ void k4_phase1_slow(
    const unsigned short* base, int i0, int jc, const float* w, float A,
    float Bv, int swzc, unsigned short* gT, int q, bf16x8* raw) {
  float w0[10], w1[10], w2[10];
  loadrow10(base + (ptrdiff_t)(i0 - 1) * 768, i0 >= 1, jc, w0);
  loadrow10(base + (ptrdiff_t)i0 * 768, true, jc, w1);
  raw[0] = packrow(w1);
#pragma unroll
  for (int r = 0; r < 4; ++r) {
    const int gi = i0 + r + 1;
    loadrow10(base + (ptrdiff_t)gi * 768, gi < 768, jc, w2);
    if (r < 3) raw[r + 1] = packrow(w2);
#pragma unroll
    for (int jj = 0; jj < 8; ++jj) {
      float h = w[0] * w0[jj] + w[1] * w0[jj + 1] + w[2] * w0[jj + 2] +
                w[3] * w1[jj] + w[4] * w1[jj + 1] + w[5] * w1[jj + 2] +
                w[6] * w2[jj] + w[7] * w2[jj + 1] + w[8] * w2[jj + 2];
      float z = A * h + Bv;
      const int p = r * 64 + q * 8 + jj;
      gT[p * 72 + swzc] = f2bf(gelu_fast(z));
    }
#pragma unroll
    for (int t = 0; t < 10; ++t) { w0[t] = w1[t]; w1[t] = w2[t]; }
  }
}

// ---------------------------------------------------------------------------
// K4: tile = 4 rows x 64 cols, all 64 ch. 512 threads, launch_bounds(512,4).
// XCD-chunked swizzle (grid 4608 = 8*576); non-temporal out stores keep
// xp resident in L2/L3. GN affine computed per block (k3b folded).
// ---------------------------------------------------------------------------
__global__ __launch_bounds__(512, 4) void k4_final(
    const unsigned short* __restrict__ xp, const float* __restrict__ stats,
    const float* __restrict__ gnw, const float* __restrict__ gnb,
    const float* __restrict__ dww, const float* __restrict__ pww,
    const float* __restrict__ pwb, float* __restrict__ out) {
  __shared__ __align__(16) unsigned short gT[256 * 72];  // phase3: oT[64][264]
  __shared__ __align__(16) unsigned short pwF[64 * 72];  // [co][ci]
  __shared__ float dwl[576];
  __shared__ float afl[128];
  __shared__ float pwbl[64];
  const int tid = threadIdx.x;
  const int bx0 = blockIdx.x;
  const int bx = (bx0 & 7) * 576 + (bx0 >> 3);   // bijective: 4608 = 8*576
  const int jt = bx % 12;
  const int it = (bx / 12) % 192;
  const int b = bx / (12 * 192);
  const int i0 = it * 4, j0 = jt * 64;

  {  // stage pwF (bf16)
    const int co = tid >> 3, ci0 = (tid & 7) * 8;
    float4 f0 = *(const float4*)&pww[co * 64 + ci0];
    float4 f1 = *(const float4*)&pww[co * 64 + ci0 + 4];
    *(ushort4*)&pwF[co * 72 + ci0] =
        make_ushort4(f2bf(f0.x), f2bf(f0.y), f2bf(f0.z), f2bf(f0.w));
    *(ushort4*)&pwF[co * 72 + ci0 + 4] =
        make_ushort4(f2bf(f1.x), f2bf(f1.y), f2bf(f1.z), f2bf(f1.w));
  }
  for (int idx = tid; idx < 576; idx += 512) dwl[idx] = dww[idx];
  if (tid < 64) {  // GN affine per channel (k3b folded)
    const int cc = tid, grp = cc >> 1;
    const float s1 = stats[(b * 32 + grp) * 2];
    const float s2 = stats[(b * 32 + grp) * 2 + 1];
    const float N = 2.f * 768.f * 768.f;
    const float m = s1 / N;
    const float v = s2 / N - m * m;
    const float rsg = rsqrtf(v + EPS_);
    const float A = rsg * gnw[cc];
    afl[cc * 2] = A;
    afl[cc * 2 + 1] = gnb[cc] - m * A;
    pwbl[cc] = pwb[cc];
  }
  __syncthreads();

  const int c = tid >> 3, q = tid & 7;
  bf16x8 raw[4];
  {  // phase 1
    const float* w = &dwl[c * 9];
    const float A = afl[c * 2], Bv = afl[c * 2 + 1];
    const unsigned short* base = xp + (size_t)(b * 64 + c) * 768 * 768;
    const int jc = j0 + q * 8;
    const int swzc = (((c >> 3) ^ q) << 3) + (c & 7);
    if (it >= 1 && it <= 190 && jt >= 1 && jt <= 10)
      k4_phase1_fast(base, i0, jc, w, A, Bv, swzc, gT, q, raw);
    else
      k4_phase1_slow(base, i0, jc, w, A, Bv, swzc, gT, q, raw);
  }
  __syncthreads();

  // phase 2: MFMA 1x1.  D[pixel][co], A = gT (swizzled chunks), B = pwF
  const int lane = tid & 63, wv = tid >> 6;
  const int g = lane >> 4, l15 = lane & 15;
  f32x4 acc[2][4];
#pragma unroll
  for (int mt = 0; mt < 2; ++mt)
#pragma unroll
    for (int nt = 0; nt < 4; ++nt) acc[mt][nt] = (f32x4){0.f, 0.f, 0.f, 0.f};

#pragma unroll
  for (int kk = 0; kk < 2; ++kk) {
    const int p0 = wv * 32 + l15;
    const int p1 = p0 + 16;
    const int cc0 = (4 * kk + g) ^ ((p0 >> 3) & 7);
    const int cc1 = (4 * kk + g) ^ ((p1 >> 3) & 7);
    bf16x8 a0 = *(const bf16x8*)&gT[p0 * 72 + cc0 * 8];
    bf16x8 a1 = *(const bf16x8*)&gT[p1 * 72 + cc1 * 8];
#pragma unroll
    for (int nt = 0; nt < 4; ++nt) {
      bf16x8 bv = *(const bf16x8*)&pwF[(nt * 16 + l15) * 72 + kk * 32 + g * 8];
      acc[0][nt] = __builtin_amdgcn_mfma_f32_16x16x32_bf16(a0, bv, acc[0][nt], 0, 0, 0);
      acc[1][nt] = __builtin_amdgcn_mfma_f32_16x16x32_bf16(a1, bv, acc[1][nt], 0, 0, 0);
    }
  }
  __syncthreads();  // all gT reads done before oT overwrite

  // phase 2b: conv results -> oT[co][264] (bf16), reusing gT memory
  unsigned short* oT = gT;
#pragma unroll
  for (int mt = 0; mt < 2; ++mt) {
#pragma unroll
    for (int nt = 0; nt < 4; ++nt) {
      const int co = nt * 16 + l15;
      const int p0 = wv * 32 + mt * 16 + g * 4;
      f32x4 a = acc[mt][nt];
      ushort4 u = make_ushort4(f2bf(a[0]), f2bf(a[1]), f2bf(a[2]), f2bf(a[3]));
      *(ushort4*)&oT[co * 264 + p0] = u;
    }
  }
  __syncthreads();

  // phase 3: out = xp(reg) + conv(oT) + bias; non-temporal stores
  {
    const float pb = pwbl[c];
    const size_t rowbase = ((size_t)(b * 64 + c) * 768 + i0) * 768 + j0 + q * 8;
#pragma unroll
    for (int r = 0; r < 4; ++r) {
      bf16x8 cv = *(const bf16x8*)&oT[c * 264 + r * 64 + q * 8];
      bf16x8 xv = raw[r];
      f32x4 o0, o1;
      o0[0] = bf2f((unsigned short)xv[0]) + bf2f((unsigned short)cv[0]) + pb;
      o0[1] = bf2f((unsigned short)xv[1]) + bf2f((unsigned short)cv[1]) + pb;
      o0[2] = bf2f((unsigned short)xv[2]) + bf2f((unsigned short)cv[2]) + pb;
      o0[3] = bf2f((unsigned short)xv[3]) + bf2f((unsigned short)cv[3]) + pb;
      o1[0] = bf2f((unsigned short)xv[4]) + bf2f((unsigned short)cv[4]) + pb;
      o1[1] = bf2f((unsigned short)xv[5]) + bf2f((unsigned short)cv[5]) + pb;
      o1[2] = bf2f((unsigned short)xv[6]) + bf2f((unsigned short)cv[6]) + pb;
      o1[3] = bf2f((unsigned short)xv[7]) + bf2f((unsigned short)cv[7]) + pb;
      float* op = out + rowbase + (size_t)r * 768;
      __builtin_nontemporal_store(o0, reinterpret_cast<f32x4*>(op));
      __builtin_nontemporal_store(o1, reinterpret_cast<f32x4*>(op + 4));
    }
  }
}

// ---------------------------------------------------------------------------
extern "C" void kernel_launch(void* const* d_in, const int* in_sizes, int n_in,
                              void* d_out, int out_size, void* d_ws,
                              size_t ws_size, hipStream_t stream) {
  const float* x_pw = (const float*)d_in[0];
  const float* x    = (const float*)d_in[1];
  const float* Wsl  = (const float*)d_in[2];
  const float* bsl  = (const float*)d_in[3];
  const float* Wop  = (const float*)d_in[4];
  const float* bop  = (const float*)d_in[5];
  const float* lnw  = (const float*)d_in[6];
  const float* lnb  = (const float*)d_in[7];
  const float* dww  = (const float*)d_in[8];
  const float* gnw  = (const float*)d_in[9];
  const float* gnb  = (const float*)d_in[10];
  const float* pww  = (const float*)d_in[11];
  const float* pwb  = (const float*)d_in[12];
  float* out = (float*)d_out;

  char* ws = (char*)d_ws;
  unsigned short* a_bf = (unsigned short*)ws;             // 196608 B
  float* stats  = (float*)(ws + 196608);                  // 512 B
  unsigned short* xpbuf = (unsigned short*)(ws + 262144); // 151 MB bf16

  k1_proj<<<24, 256, 0, stream>>>(x, Wsl, bsl, a_bf, stats);
  k2_outer<<<2 * 768 * 12, 256, 0, stream>>>(x_pw, a_bf, Wop, bop, lnw, lnb,
                                             xpbuf);
  k3_stats<<<2 * 64 * 24, 384, 0, stream>>>(xpbuf, dww, stats);
  k4_final<<<2 * 192 * 12, 512, 0, stream>>>(xpbuf, stats, gnw, gnb, dww, pww,
                                             pwb, out);
}